// Round 10
// baseline (453.464 us; speedup 1.0000x reference)
//
#include <hip/hip_runtime.h>
#include <math.h>

#define B_GROUPS 64
#define C_DIM 256
#define IN_DIM 512
#define EMB_DIM 512
#define NHEADS 8
#define HDIM 32

typedef __attribute__((ext_vector_type(8))) short short8v;   // 8 bf16 = 4 VGPR
typedef __attribute__((ext_vector_type(4))) float float4v;   // mfma acc

// split fp32 -> bf16 hi (truncate, residual exact) + bf16 lo (rounded)
__device__ __forceinline__ void split2(float x, short& hi, short& lo) {
  unsigned u = __float_as_uint(x);
  hi = (short)(u >> 16);
  float l = x - __uint_as_float(u & 0xffff0000u);   // exact
  unsigned ul = __float_as_uint(l);
  lo = (short)((ul + 0x8000u) >> 16);
}

// global -> LDS direct copy, 16B per lane (dest linear: base + lane*16)
#define GLL(src, dst) __builtin_amdgcn_global_load_lds( \
    (const __attribute__((address_space(1))) void*)(src), \
    (__attribute__((address_space(3))) void*)(dst), 16, 0, 0)

// ---------------- per-group starts via binary search ----------------
__global__ void starts_kernel(const int* __restrict__ bx, int nx,
                              const int* __restrict__ be, int ne,
                              int* __restrict__ sx, int* __restrict__ se) {
  int b = threadIdx.x;
  if (b > B_GROUPS) return;
  int lo = 0, hi = nx;
  while (lo < hi) { int mid = (lo + hi) >> 1; if (bx[mid] < b) lo = mid + 1; else hi = mid; }
  sx[b] = lo;
  lo = 0; hi = ne;
  while (lo < hi) { int mid = (lo + hi) >> 1; if (be[mid] < b) lo = mid + 1; else hi = mid; }
  se[b] = lo;
}

// ---------------- prep: split enc,x ; transpose+split weights ----------------
__global__ __launch_bounds__(256) void prep_kernel(
    const float* __restrict__ enc, const float* __restrict__ x,
    const float* __restrict__ W1, const float* __restrict__ W2,
    const float* __restrict__ Wq, const float* __restrict__ Wk,
    const float* __restrict__ Wv, const float* __restrict__ Wp,
    short* __restrict__ encH, short* __restrict__ encL,
    short* __restrict__ xH, short* __restrict__ xL,
    short* __restrict__ wbuf, int nEnc, int nX) {
  int gid = blockIdx.x * blockDim.x + threadIdx.x;
  int stride = gridDim.x * blockDim.x;
  for (int i = gid; i < nEnc; i += stride) { short h,l; split2(enc[i],h,l); encH[i]=h; encL[i]=l; }
  for (int i = gid; i < nX;   i += stride) { short h,l; split2(x[i],h,l);   xH[i]=h;   xL[i]=l; }
  short* w1tH = wbuf;               short* w1tL = w1tH + 512*512;
  short* w2tH = w1tL + 512*512;     short* w2tL = w2tH + 256*512;
  short* wqtH = w2tL + 256*512;     short* wqtL = wqtH + 256*256;
  short* wktH = wqtL + 256*256;     short* wktL = wktH + 256*256;
  short* wvtH = wktL + 256*256;     short* wvtL = wvtH + 256*256;
  short* wptH = wvtL + 256*256;     short* wptL = wptH + 256*256;
  for (int i = gid; i < 512*512; i += stride) {
    int n = i >> 9, k = i & 511; short h,l;
    split2(W1[k*512 + n], h, l); w1tH[i] = h; w1tL[i] = l;
  }
  for (int i = gid; i < 256*512; i += stride) {
    int n = i >> 9, k = i & 511; short h,l;
    split2(W2[k*256 + n], h, l); w2tH[i] = h; w2tL[i] = l;
  }
  for (int i = gid; i < 256*256; i += stride) {
    int n = i >> 8, k = i & 255; int s = k*256 + n; short h,l;
    split2(Wq[s],h,l); wqtH[i]=h; wqtL[i]=l;
    split2(Wk[s],h,l); wktH[i]=h; wktL[i]=l;
    split2(Wv[s],h,l); wvtH[i]=h; wvtL[i]=l;
    split2(Wp[s],h,l); wptH[i]=h; wptL[i]=l;
  }
}

// ---------------- bf16x2-split MFMA GEMM: 128x128 tile, 4 waves ------------
// (unchanged from R9 — harness-verified)
__global__ __launch_bounds__(256) void gemm_mfma(
    const short* __restrict__ Ah0, const short* __restrict__ Al0,
    const short* __restrict__ Wh0, const short* __restrict__ Wl0,
    const float* __restrict__ bias0, float* __restrict__ Cf0,
    short* __restrict__ Ch0, short* __restrict__ Cl0,
    int K0, int N0, int act0, int emit0,
    const short* __restrict__ Ah1, const short* __restrict__ Al1,
    const short* __restrict__ Wh1, const short* __restrict__ Wl1,
    const float* __restrict__ bias1, float* __restrict__ Cf1,
    short* __restrict__ Ch1, short* __restrict__ Cl1,
    int K1, int N1, int act1, int emit1,
    int xsplit, int Mrows) {
  __shared__ short AsH[4096], AsL[4096], WsH[4096], WsL[4096];   // 4x8KB

  int bxi = blockIdx.x;
  const short *Ah, *Al, *Wh, *Wl; const float* bias; float* Cf; short *Ch, *Cl;
  int K, N, act, emit;
  if (bxi < xsplit) {
    Ah=Ah0; Al=Al0; Wh=Wh0; Wl=Wl0; bias=bias0; Cf=Cf0; Ch=Ch0; Cl=Cl0;
    K=K0; N=N0; act=act0; emit=emit0;
  } else {
    bxi -= xsplit;
    Ah=Ah1; Al=Al1; Wh=Wh1; Wl=Wl1; bias=bias1; Cf=Cf1; Ch=Ch1; Cl=Cl1;
    K=K1; N=N1; act=act1; emit=emit1;
  }
  int bm = blockIdx.y * 128;
  int bn = bxi * 128;

  int tid = threadIdx.x;
  int wv = tid >> 6, lane = tid & 63;
  int wr = (wv >> 1) * 64, wc = (wv & 1) * 64;
  int laneM = lane & 15, laneK = lane >> 4;

  int Ga = wv * 128 + lane;
  int Gb = Ga + 64;
  int rA = Ga >> 2, gA = (Ga & 3) ^ ((rA >> 1) & 3);
  int rB = Gb >> 2, gB = (Gb & 3) ^ ((rB >> 1) & 3);
  const short* pAh0 = Ah + (size_t)(bm + rA) * K + gA * 8;
  const short* pAh1 = Ah + (size_t)(bm + rB) * K + gB * 8;
  const short* pAl0 = Al + (size_t)(bm + rA) * K + gA * 8;
  const short* pAl1 = Al + (size_t)(bm + rB) * K + gB * 8;
  const short* pWh0 = Wh + (size_t)(bn + rA) * K + gA * 8;
  const short* pWh1 = Wh + (size_t)(bn + rB) * K + gB * 8;
  const short* pWl0 = Wl + (size_t)(bn + rA) * K + gA * 8;
  const short* pWl1 = Wl + (size_t)(bn + rB) * K + gB * 8;
  short* dAH0 = AsH + wv * 1024;  short* dAH1 = dAH0 + 512;
  short* dAL0 = AsL + wv * 1024;  short* dAL1 = dAL0 + 512;
  short* dWH0 = WsH + wv * 1024;  short* dWH1 = dWH0 + 512;
  short* dWL0 = WsL + wv * 1024;  short* dWL1 = dWL0 + 512;

  int am[4], bo[4];
#pragma unroll
  for (int m = 0; m < 4; ++m) {
    int row = wr + m * 16 + laneM;
    am[m] = row * 32 + ((laneK ^ ((row >> 1) & 3)) << 3);
  }
#pragma unroll
  for (int n = 0; n < 4; ++n) {
    int row = wc + n * 16 + laneM;
    bo[n] = row * 32 + ((laneK ^ ((row >> 1) & 3)) << 3);
  }

  float4v acc[4][4];
  float4v z4 = {0.f, 0.f, 0.f, 0.f};
#pragma unroll
  for (int m = 0; m < 4; ++m)
#pragma unroll
    for (int n = 0; n < 4; ++n) acc[m][n] = z4;

  int nsteps = K >> 5;
  for (int t = 0; t < nsteps; ++t) {
    GLL(pAh0, dAH0); GLL(pAh1, dAH1);
    GLL(pAl0, dAL0); GLL(pAl1, dAL1);
    GLL(pWh0, dWH0); GLL(pWh1, dWH1);
    GLL(pWl0, dWL0); GLL(pWl1, dWL1);
    pAh0 += 32; pAh1 += 32; pAl0 += 32; pAl1 += 32;
    pWh0 += 32; pWh1 += 32; pWl0 += 32; pWl1 += 32;
    __syncthreads();

    short8v ah[4], al[4], bh[4], bl[4];
#pragma unroll
    for (int m = 0; m < 4; ++m) {
      ah[m] = *(const short8v*)(AsH + am[m]);
      al[m] = *(const short8v*)(AsL + am[m]);
    }
#pragma unroll
    for (int n = 0; n < 4; ++n) {
      bh[n] = *(const short8v*)(WsH + bo[n]);
      bl[n] = *(const short8v*)(WsL + bo[n]);
    }
#pragma unroll
    for (int m = 0; m < 4; ++m)
#pragma unroll
      for (int n = 0; n < 4; ++n) {
        acc[m][n] = __builtin_amdgcn_mfma_f32_16x16x32_bf16(ah[m], bh[n], acc[m][n], 0, 0, 0);
        acc[m][n] = __builtin_amdgcn_mfma_f32_16x16x32_bf16(ah[m], bl[n], acc[m][n], 0, 0, 0);
        acc[m][n] = __builtin_amdgcn_mfma_f32_16x16x32_bf16(al[m], bh[n], acc[m][n], 0, 0, 0);
      }
    __syncthreads();
  }

  float bvn[4];
#pragma unroll
  for (int n = 0; n < 4; ++n) bvn[n] = bias[bn + wc + n * 16 + laneM];
#pragma unroll
  for (int m = 0; m < 4; ++m)
#pragma unroll
    for (int n = 0; n < 4; ++n)
#pragma unroll
      for (int r = 0; r < 4; ++r) {
        float vv = acc[m][n][r] + bvn[n];
        if (act) vv = 0.5f * vv * (1.0f + erff(vv * 0.70710678118654752f));
        size_t row = (size_t)(bm + wr + m * 16 + laneK * 4 + r);
        int col = bn + wc + n * 16 + laneM;
        if (emit == 0) {
          Cf[row * N + col] = vv;
        } else if (emit == 1) {
          short hh, ll; split2(vv, hh, ll);
          Ch[row * N + col] = hh; Cl[row * N + col] = ll;
        } else if (emit == 2) {   // head-major [NH][Mrows][32]
          size_t idx = ((size_t)(col >> 5) * Mrows + row) * 32 + (col & 31);
          short hh, ll; split2(vv, hh, ll);
          Ch[idx] = hh; Cl[idx] = ll;
        } else {                  // V^T [NH][32][Mrows]
          size_t idx = ((size_t)(col >> 5) * 32 + (col & 31)) * Mrows + row;
          short hh, ll; split2(vv, hh, ll);
          Ch[idx] = hh; Cl[idx] = ll;
        }
      }
}

// ---------------- LayerNorm over last dim (256) -> split bf16 --------------
__global__ __launch_bounds__(256) void ln_kernel(const float* __restrict__ h,
    const float* __restrict__ w, const float* __restrict__ b,
    short* __restrict__ oH, short* __restrict__ oL, int M) {
  int row = blockIdx.x * 4 + (threadIdx.x >> 6);
  int lane = threadIdx.x & 63;
  if (row >= M) return;
  float4 v = *(const float4*)&h[(size_t)row * C_DIM + lane * 4];
  float s  = v.x + v.y + v.z + v.w;
  float s2 = v.x * v.x + v.y * v.y + v.z * v.z + v.w * v.w;
#pragma unroll
  for (int off = 1; off < 64; off <<= 1) { s += __shfl_xor(s, off); s2 += __shfl_xor(s2, off); }
  float mu  = s  * (1.0f / 256.0f);
  float var = s2 * (1.0f / 256.0f) - mu * mu;
  float inv = rsqrtf(var + 1e-5f);
  float4 wv = *(const float4*)&w[lane * 4];
  float4 bv = *(const float4*)&b[lane * 4];
  float o0 = (v.x - mu) * inv * wv.x + bv.x;
  float o1 = (v.y - mu) * inv * wv.y + bv.y;
  float o2 = (v.z - mu) * inv * wv.z + bv.z;
  float o3 = (v.w - mu) * inv * wv.w + bv.w;
  short h0,h1,h2,h3,l0,l1,l2,l3;
  split2(o0,h0,l0); split2(o1,h1,l1); split2(o2,h2,l2); split2(o3,h3,l3);
  size_t off = (size_t)row * C_DIM + lane * 4;
  *(short4*)&oH[off] = make_short4(h0,h1,h2,h3);
  *(short4*)&oL[off] = make_short4(l0,l1,l2,l3);
}

// ---------------- MFMA flash attention v2 ----------------------------------
// Changes vs R9 (same grid/swizzle/frag conventions, no barriers):
// 1. T14 prefetch: K(t+1) issued right after QK^T(t) consumes K(t); V+mask
//    issued at iteration top (hidden under QK^T+softmax). Registers only.
// 2. Swapped QK^T: mfma(K,Q) -> D = S^T; lane (lm,lk) holds S[q=lm][kv=
//    t*16+lk*4+r]. Softmax = 15 local fmax + shfl_xor(16,32) [2 shfl vs 32],
//    single alpha/exp chain per lane; alpha re-broadcast to acc rows with
//    4 shfl (src lane = q < 16, all lanes active).
// 3. P->LDS: 8x ds_write_b64 (short4-packed) into rows[72] with granule slot
//    (g - 2*lm)&7; b128 reads land on 8 distinct 16B positions per 8-lane
//    group (conflict-free). Same-wave RAW (wave-private tile), no barriers.
__global__ __launch_bounds__(256, 3) void attn_mfma(
    const short* __restrict__ qh, const short* __restrict__ ql,   // [NH][Nx][32]
    const short* __restrict__ kh, const short* __restrict__ kl,   // [NH][Ne][32]
    const short* __restrict__ vh, const short* __restrict__ vl,   // [NH][32][Ne]
    const int* __restrict__ sx, const int* __restrict__ se,
    const int* __restrict__ emask,
    short* __restrict__ yH, short* __restrict__ yL,               // [Nx][256]
    int Nx, int Ne) {
  __shared__ short Ph[4][16][72];
  __shared__ short Pl[4][16][72];

  int bid = blockIdx.x;
  int work = ((bid & 7) << 9) + (bid >> 3);   // same (b,hd) group -> same XCD
  int qt8 = work & 7;
  int bh  = work >> 3;
  int b   = bh & 63;
  int hd  = bh >> 6;

  int xs = sx[b], lx = sx[b + 1] - xs;
  int es = se[b], le = se[b + 1] - es;

  int tid = threadIdx.x;
  int wv = tid >> 6, lane = tid & 63;
  int qt = qt8 * 4 + wv;                  // 0..31 q-tiles of 16
  if (qt * 16 >= lx) return;              // wave-uniform

  int lm = lane & 15, lk = lane >> 4;

  // Q frag (B-operand of swapped QK^T): lane holds Q[q=lm][k=lk*8+j]
  int qa = xs + min(qt * 16 + lm, lx - 1);
  size_t qoff = ((size_t)hd * Nx + qa) * 32 + lk * 8;
  short8v qfh = *(const short8v*)(qh + qoff);
  short8v qfl = *(const short8v*)(ql + qoff);

  float4v acc0 = {0.f,0.f,0.f,0.f}, acc1 = {0.f,0.f,0.f,0.f};
  float mrun = -INFINITY, lrun = 0.f;
  const float scale = 0.17677669529663689f;  // 1/sqrt(32)

  int kvend = es + le;
  int kb0 = (es >> 6) << 6;

  // ---- prologue: K frags for first tile (A-operand: row=kv=lm, k=lk*8+j)
  short8v kfh[4], kfl[4];
#pragma unroll
  for (int t = 0; t < 4; ++t) {
    int tokc = min(kb0 + t * 16 + lm, Ne - 1);
    size_t koff = ((size_t)hd * Ne + tokc) * 32 + lk * 8;
    kfh[t] = *(const short8v*)(kh + koff);
    kfl[t] = *(const short8v*)(kl + koff);
  }

  for (int kb = kb0; kb < kvend; kb += 64) {
    // ---- issue V loads (used at PV, covered by QK^T+softmax)
    short8v v0h[2], v0l[2], v1h[2], v1l[2];
#pragma unroll
    for (int c = 0; c < 2; ++c) {
      int tokb = kb + c * 32 + lk * 8;
      if (tokb > Ne - 8) tokb = Ne - 8;     // clamped junk is masked (P=0)
      size_t va = ((size_t)hd * 32 + lm) * Ne + tokb;
      size_t vb = ((size_t)hd * 32 + 16 + lm) * Ne + tokb;
      v0h[c] = *(const short8v*)(vh + va);
      v0l[c] = *(const short8v*)(vl + va);
      v1h[c] = *(const short8v*)(vh + vb);
      v1l[c] = *(const short8v*)(vl + vb);
    }
    // ---- issue mask loads (int4 per tile; lane covers kv=t*16+lk*4+r)
    int4 mk[4];
#pragma unroll
    for (int t = 0; t < 4; ++t) {
      int tb = kb + t * 16 + lk * 4;
      mk[t] = *(const int4*)(emask + min(tb, Ne - 4));
    }

    // ---- swapped QK^T: S^T = K·Q^T; lane holds S[q=lm][kv=t*16+lk*4+r]
    float4v s[4];
#pragma unroll
    for (int t = 0; t < 4; ++t) {
      float4v z = {0.f,0.f,0.f,0.f};
      z = __builtin_amdgcn_mfma_f32_16x16x32_bf16(kfh[t], qfh, z, 0, 0, 0);
      z = __builtin_amdgcn_mfma_f32_16x16x32_bf16(kfh[t], qfl, z, 0, 0, 0);
      z = __builtin_amdgcn_mfma_f32_16x16x32_bf16(kfl[t], qfh, z, 0, 0, 0);
      s[t] = z;
    }

    // ---- prefetch next tile's K (K regs dead after QK^T issue)
    {
      int kbn = (kb + 64 < kvend) ? kb + 64 : kb;
#pragma unroll
      for (int t = 0; t < 4; ++t) {
        int tokc = min(kbn + t * 16 + lm, Ne - 1);
        size_t koff = ((size_t)hd * Ne + tokc) * 32 + lk * 8;
        kfh[t] = *(const short8v*)(kh + koff);
        kfl[t] = *(const short8v*)(kl + koff);
      }
    }

    // ---- per-lane online softmax for q = lm
    float pv[4][4];
    float mloc = -INFINITY;
#pragma unroll
    for (int t = 0; t < 4; ++t) {
      int tb = kb + t * 16 + lk * 4;
#pragma unroll
      for (int r = 0; r < 4; ++r) {
        int tok = tb + r;
        int mval = (r == 0) ? mk[t].x : (r == 1) ? mk[t].y : (r == 2) ? mk[t].z : mk[t].w;
        float bias = (tok >= es && tok < kvend && mval != 0) ? 0.f : -1e30f;
        float pp = s[t][r] * scale + bias;
        pv[t][r] = pp;
        mloc = fmaxf(mloc, pp);
      }
    }
    mloc = fmaxf(mloc, __shfl_xor(mloc, 16));
    mloc = fmaxf(mloc, __shfl_xor(mloc, 32));
    float mnew = fmaxf(mrun, mloc);
    float alpha = __expf(mrun - mnew);      // first tile: exp(-inf)=0
    float lloc = 0.f;
#pragma unroll
    for (int t = 0; t < 4; ++t) {
      short hs[4], ls[4];
#pragma unroll
      for (int r = 0; r < 4; ++r) {
        float e = __expf(pv[t][r] - mnew);
        lloc += e;
        split2(e, hs[r], ls[r]);
      }
      int kvg = 2 * t + (lk >> 1);          // granule of kv = t*16+lk*4
      int gs = (kvg - 2 * lm) & 7;          // rotate -> conflict-free reads
      int off = gs * 8 + (lk & 1) * 4;
      *(short4*)&Ph[wv][lm][off] = make_short4(hs[0], hs[1], hs[2], hs[3]);
      *(short4*)&Pl[wv][lm][off] = make_short4(ls[0], ls[1], ls[2], ls[3]);
    }
    lloc += __shfl_xor(lloc, 16);
    lloc += __shfl_xor(lloc, 32);
    lrun = lrun * alpha + lloc;
    mrun = mnew;

    // ---- rescale acc (alpha lives at q=lm lanes; acc rows are q=lk*4+r)
#pragma unroll
    for (int r = 0; r < 4; ++r) {
      float aq = __shfl(alpha, lk * 4 + r);
      acc0[r] *= aq; acc1[r] *= aq;
    }

    // ---- PV: A=P (row=q=lm, k=kv from swizzled LDS), B=V^T rows
#pragma unroll
    for (int c = 0; c < 2; ++c) {
      int gs = ((4 * c + lk) - 2 * lm) & 7;
      short8v pfh = *(const short8v*)&Ph[wv][lm][gs * 8];
      short8v pfl = *(const short8v*)&Pl[wv][lm][gs * 8];
      acc0 = __builtin_amdgcn_mfma_f32_16x16x32_bf16(pfh, v0h[c], acc0, 0, 0, 0);
      acc0 = __builtin_amdgcn_mfma_f32_16x16x32_bf16(pfh, v0l[c], acc0, 0, 0, 0);
      acc0 = __builtin_amdgcn_mfma_f32_16x16x32_bf16(pfl, v0h[c], acc0, 0, 0, 0);
      acc1 = __builtin_amdgcn_mfma_f32_16x16x32_bf16(pfh, v1h[c], acc1, 0, 0, 0);
      acc1 = __builtin_amdgcn_mfma_f32_16x16x32_bf16(pfh, v1l[c], acc1, 0, 0, 0);
      acc1 = __builtin_amdgcn_mfma_f32_16x16x32_bf16(pfl, v1h[c], acc1, 0, 0, 0);
    }
  }

  // ---- output: q = qt*16 + lk*4 + r, d = {lm, 16+lm}; invl via shfl
  float invl = (lrun > 0.f) ? 1.0f / lrun : 0.f;
  float iq[4];
#pragma unroll
  for (int r = 0; r < 4; ++r) iq[r] = __shfl(invl, lk * 4 + r);
#pragma unroll
  for (int r = 0; r < 4; ++r) {
    int q = qt * 16 + lk * 4 + r;
    if (q >= lx) continue;
    size_t base = (size_t)(xs + q) * C_DIM + hd * HDIM;
    short hh, ll;
    split2(acc0[r] * iq[r], hh, ll); yH[base + lm] = hh;      yL[base + lm] = ll;
    split2(acc1[r] * iq[r], hh, ll); yH[base + 16 + lm] = hh; yL[base + 16 + lm] = ll;
  }
}

// ---------------- launch ----------------
extern "C" void kernel_launch(void* const* d_in, const int* in_sizes, int n_in,
                              void* d_out, int out_size, void* d_ws, size_t ws_size,
                              hipStream_t stream) {
  const float* x    = (const float*)d_in[0];
  const int*   bx   = (const int*)d_in[1];
  const int*   be   = (const int*)d_in[2];
  const float* enc  = (const float*)d_in[3];
  const int*   msk  = (const int*)d_in[4];
  const float* Wq   = (const float*)d_in[5];
  const float* bq   = (const float*)d_in[6];
  const float* Wk   = (const float*)d_in[7];
  const float* bk   = (const float*)d_in[8];
  const float* Wv   = (const float*)d_in[9];
  const float* bv   = (const float*)d_in[10];
  const float* Wp   = (const float*)d_in[11];
  const float* bp   = (const float*)d_in[12];
  const float* W1   = (const float*)d_in[13];
  const float* b1   = (const float*)d_in[14];
  const float* W2   = (const float*)d_in[15];
  const float* b2   = (const float*)d_in[16];
  const float* lnw  = (const float*)d_in[17];
  const float* lnb  = (const float*)d_in[18];
  float* out = (float*)d_out;

  int Nx = in_sizes[0] / C_DIM;    // 24576 (multiple of 128, == Ne)
  int Ne = in_sizes[3] / IN_DIM;

  char* ws = (char*)d_ws;
  int* sx = (int*)ws;
  int* se = sx + 80;

  short* encH = (short*)(ws + 4096);                 // Ne*512
  short* encL = encH + (size_t)Ne * IN_DIM;          // Ne*512
  short* xH   = encL + (size_t)Ne * IN_DIM;          // Nx*256 (later yH)
  short* xL   = xH + (size_t)Nx * C_DIM;             // Nx*256 (later yL)
  short* gLo  = xL + (size_t)Nx * C_DIM;             // Ne*512 (later vH|vL)
  short* qHh  = gLo + (size_t)Ne * EMB_DIM;          // Nx*256
  short* qHl  = qHh + (size_t)Nx * C_DIM;            // Nx*256
  short* wbuf = qHl + (size_t)Nx * C_DIM;            // 1.31M shorts
  // reuses:
  short* gHi  = (short*)d_out;                       // G1 hi; dead after G2
  float* hbuf = (float*)encH;                        // enc splits dead post-G1
  short* hsH  = encL;
  short* hsL  = encL + (size_t)Ne * C_DIM;
  short* kH   = (short*)d_out;                       // after G2 (g dead)
  short* kL   = kH + (size_t)Ne * C_DIM;
  short* vH   = gLo;                                 // gLo dead after G2
  short* vL   = gLo + (size_t)Ne * C_DIM;

  short* w1tH = wbuf;               short* w1tL = w1tH + 512*512;
  short* w2tH = w1tL + 512*512;     short* w2tL = w2tH + 256*512;
  short* wqtH = w2tL + 256*512;     short* wqtL = wqtH + 256*256;
  short* wktH = wqtL + 256*256;     short* wktL = wktH + 256*256;
  short* wvtH = wktL + 256*256;     short* wvtL = wvtH + 256*256;
  short* wptH = wvtL + 256*256;     short* wptL = wptH + 256*256;

  prep_kernel<<<2048, 256, 0, stream>>>(enc, x, W1, W2, Wq, Wk, Wv, Wp,
      encH, encL, xH, xL, wbuf, Ne * IN_DIM, Nx * C_DIM);
  starts_kernel<<<1, 128, 0, stream>>>(bx, Nx, be, Ne, sx, se);

  int gy = Nx / 128;

  // G1: g = GELU(enc@W1+b1) -> split std ; Q: x@Wq+bq -> head-major split
  gemm_mfma<<<dim3(6, gy), 256, 0, stream>>>(
      encH, encL, w1tH, w1tL, b1, nullptr, gHi, gLo, IN_DIM, EMB_DIM, 1, 1,
      xH,   xL,   wqtH, wqtL, bq, nullptr, qHh, qHl,  C_DIM, C_DIM,  0, 2,
      4, Nx);

  // G2: h = g@W2+b2 (fp32)
  gemm_mfma<<<dim3(2, gy), 256, 0, stream>>>(
      gHi, gLo, w2tH, w2tL, b2, hbuf, nullptr, nullptr, EMB_DIM, C_DIM, 0, 0,
      gHi, gLo, w2tH, w2tL, b2, hbuf, nullptr, nullptr, EMB_DIM, C_DIM, 0, 0,
      2, Nx);

  ln_kernel<<<(Ne + 3) / 4, 256, 0, stream>>>(hbuf, lnw, lnb, hsH, hsL, Ne);

  // KV: K -> head-major split ; V -> V^T split (one A pass)
  gemm_mfma<<<dim3(4, gy), 256, 0, stream>>>(
      hsH, hsL, wktH, wktL, bk, nullptr, kH, kL, C_DIM, C_DIM, 0, 2,
      hsH, hsL, wvtH, wvtL, bv, nullptr, vH, vL, C_DIM, C_DIM, 0, 3,
      2, Nx);

  // MFMA attention -> y splits (over x region; x dead after G1)
  attn_mfma<<<dim3(4096), 256, 0, stream>>>(
      qHh, qHl, kH, kL, vH, vL, sx, se, msk, xH, xL, Nx, Ne);

  // P: out = y@Wp+bp (fp32)
  gemm_mfma<<<dim3(2, gy), 256, 0, stream>>>(
      xH, xL, wptH, wptL, bp, out, nullptr, nullptr, C_DIM, C_DIM, 0, 0,
      xH, xL, wptH, wptL, bp, out, nullptr, nullptr, C_DIM, C_DIM, 0, 0,
      2, Nx);
}

// Round 11
// 361.337 us; speedup vs baseline: 1.2550x; 1.2550x over previous
//
#include <hip/hip_runtime.h>
#include <math.h>

#define B_GROUPS 64
#define C_DIM 256
#define IN_DIM 512
#define EMB_DIM 512
#define NHEADS 8
#define HDIM 32

typedef __attribute__((ext_vector_type(8))) short short8v;   // 8 bf16 = 4 VGPR
typedef __attribute__((ext_vector_type(4))) float float4v;   // mfma acc

// split fp32 -> bf16 hi (truncate, residual exact) + bf16 lo (rounded)
__device__ __forceinline__ void split2(float x, short& hi, short& lo) {
  unsigned u = __float_as_uint(x);
  hi = (short)(u >> 16);
  float l = x - __uint_as_float(u & 0xffff0000u);   // exact
  unsigned ul = __float_as_uint(l);
  lo = (short)((ul + 0x8000u) >> 16);
}

// global -> LDS direct copy, 16B per lane (dest linear: base + lane*16)
#define GLL(src, dst) __builtin_amdgcn_global_load_lds( \
    (const __attribute__((address_space(1))) void*)(src), \
    (__attribute__((address_space(3))) void*)(dst), 16, 0, 0)

// ---------------- per-group starts via binary search ----------------
__global__ void starts_kernel(const int* __restrict__ bx, int nx,
                              const int* __restrict__ be, int ne,
                              int* __restrict__ sx, int* __restrict__ se) {
  int b = threadIdx.x;
  if (b > B_GROUPS) return;
  int lo = 0, hi = nx;
  while (lo < hi) { int mid = (lo + hi) >> 1; if (bx[mid] < b) lo = mid + 1; else hi = mid; }
  sx[b] = lo;
  lo = 0; hi = ne;
  while (lo < hi) { int mid = (lo + hi) >> 1; if (be[mid] < b) lo = mid + 1; else hi = mid; }
  se[b] = lo;
}

// ---------------- prep: split enc,x ; transpose+split weights ----------------
__global__ __launch_bounds__(256) void prep_kernel(
    const float* __restrict__ enc, const float* __restrict__ x,
    const float* __restrict__ W1, const float* __restrict__ W2,
    const float* __restrict__ Wq, const float* __restrict__ Wk,
    const float* __restrict__ Wv, const float* __restrict__ Wp,
    short* __restrict__ encH, short* __restrict__ encL,
    short* __restrict__ xH, short* __restrict__ xL,
    short* __restrict__ wbuf, int nEnc, int nX) {
  int gid = blockIdx.x * blockDim.x + threadIdx.x;
  int stride = gridDim.x * blockDim.x;
  for (int i = gid; i < nEnc; i += stride) { short h,l; split2(enc[i],h,l); encH[i]=h; encL[i]=l; }
  for (int i = gid; i < nX;   i += stride) { short h,l; split2(x[i],h,l);   xH[i]=h;   xL[i]=l; }
  short* w1tH = wbuf;               short* w1tL = w1tH + 512*512;
  short* w2tH = w1tL + 512*512;     short* w2tL = w2tH + 256*512;
  short* wqtH = w2tL + 256*512;     short* wqtL = wqtH + 256*256;
  short* wktH = wqtL + 256*256;     short* wktL = wktH + 256*256;
  short* wvtH = wktL + 256*256;     short* wvtL = wvtH + 256*256;
  short* wptH = wvtL + 256*256;     short* wptL = wptH + 256*256;
  for (int i = gid; i < 512*512; i += stride) {
    int n = i >> 9, k = i & 511; short h,l;
    split2(W1[k*512 + n], h, l); w1tH[i] = h; w1tL[i] = l;
  }
  for (int i = gid; i < 256*512; i += stride) {
    int n = i >> 9, k = i & 511; short h,l;
    split2(W2[k*256 + n], h, l); w2tH[i] = h; w2tL[i] = l;
  }
  for (int i = gid; i < 256*256; i += stride) {
    int n = i >> 8, k = i & 255; int s = k*256 + n; short h,l;
    split2(Wq[s],h,l); wqtH[i]=h; wqtL[i]=l;
    split2(Wk[s],h,l); wktH[i]=h; wktL[i]=l;
    split2(Wv[s],h,l); wvtH[i]=h; wvtL[i]=l;
    split2(Wp[s],h,l); wptH[i]=h; wptL[i]=l;
  }
}

// ---------------- bf16x2-split MFMA GEMM: 128x128 tile, 4 waves ------------
// (unchanged from R9 — harness-verified)
__global__ __launch_bounds__(256) void gemm_mfma(
    const short* __restrict__ Ah0, const short* __restrict__ Al0,
    const short* __restrict__ Wh0, const short* __restrict__ Wl0,
    const float* __restrict__ bias0, float* __restrict__ Cf0,
    short* __restrict__ Ch0, short* __restrict__ Cl0,
    int K0, int N0, int act0, int emit0,
    const short* __restrict__ Ah1, const short* __restrict__ Al1,
    const short* __restrict__ Wh1, const short* __restrict__ Wl1,
    const float* __restrict__ bias1, float* __restrict__ Cf1,
    short* __restrict__ Ch1, short* __restrict__ Cl1,
    int K1, int N1, int act1, int emit1,
    int xsplit, int Mrows) {
  __shared__ short AsH[4096], AsL[4096], WsH[4096], WsL[4096];   // 4x8KB

  int bxi = blockIdx.x;
  const short *Ah, *Al, *Wh, *Wl; const float* bias; float* Cf; short *Ch, *Cl;
  int K, N, act, emit;
  if (bxi < xsplit) {
    Ah=Ah0; Al=Al0; Wh=Wh0; Wl=Wl0; bias=bias0; Cf=Cf0; Ch=Ch0; Cl=Cl0;
    K=K0; N=N0; act=act0; emit=emit0;
  } else {
    bxi -= xsplit;
    Ah=Ah1; Al=Al1; Wh=Wh1; Wl=Wl1; bias=bias1; Cf=Cf1; Ch=Ch1; Cl=Cl1;
    K=K1; N=N1; act=act1; emit=emit1;
  }
  int bm = blockIdx.y * 128;
  int bn = bxi * 128;

  int tid = threadIdx.x;
  int wv = tid >> 6, lane = tid & 63;
  int wr = (wv >> 1) * 64, wc = (wv & 1) * 64;
  int laneM = lane & 15, laneK = lane >> 4;

  int Ga = wv * 128 + lane;
  int Gb = Ga + 64;
  int rA = Ga >> 2, gA = (Ga & 3) ^ ((rA >> 1) & 3);
  int rB = Gb >> 2, gB = (Gb & 3) ^ ((rB >> 1) & 3);
  const short* pAh0 = Ah + (size_t)(bm + rA) * K + gA * 8;
  const short* pAh1 = Ah + (size_t)(bm + rB) * K + gB * 8;
  const short* pAl0 = Al + (size_t)(bm + rA) * K + gA * 8;
  const short* pAl1 = Al + (size_t)(bm + rB) * K + gB * 8;
  const short* pWh0 = Wh + (size_t)(bn + rA) * K + gA * 8;
  const short* pWh1 = Wh + (size_t)(bn + rB) * K + gB * 8;
  const short* pWl0 = Wl + (size_t)(bn + rA) * K + gA * 8;
  const short* pWl1 = Wl + (size_t)(bn + rB) * K + gB * 8;
  short* dAH0 = AsH + wv * 1024;  short* dAH1 = dAH0 + 512;
  short* dAL0 = AsL + wv * 1024;  short* dAL1 = dAL0 + 512;
  short* dWH0 = WsH + wv * 1024;  short* dWH1 = dWH0 + 512;
  short* dWL0 = WsL + wv * 1024;  short* dWL1 = dWL0 + 512;

  int am[4], bo[4];
#pragma unroll
  for (int m = 0; m < 4; ++m) {
    int row = wr + m * 16 + laneM;
    am[m] = row * 32 + ((laneK ^ ((row >> 1) & 3)) << 3);
  }
#pragma unroll
  for (int n = 0; n < 4; ++n) {
    int row = wc + n * 16 + laneM;
    bo[n] = row * 32 + ((laneK ^ ((row >> 1) & 3)) << 3);
  }

  float4v acc[4][4];
  float4v z4 = {0.f, 0.f, 0.f, 0.f};
#pragma unroll
  for (int m = 0; m < 4; ++m)
#pragma unroll
    for (int n = 0; n < 4; ++n) acc[m][n] = z4;

  int nsteps = K >> 5;
  for (int t = 0; t < nsteps; ++t) {
    GLL(pAh0, dAH0); GLL(pAh1, dAH1);
    GLL(pAl0, dAL0); GLL(pAl1, dAL1);
    GLL(pWh0, dWH0); GLL(pWh1, dWH1);
    GLL(pWl0, dWL0); GLL(pWl1, dWL1);
    pAh0 += 32; pAh1 += 32; pAl0 += 32; pAl1 += 32;
    pWh0 += 32; pWh1 += 32; pWl0 += 32; pWl1 += 32;
    __syncthreads();

    short8v ah[4], al[4], bh[4], bl[4];
#pragma unroll
    for (int m = 0; m < 4; ++m) {
      ah[m] = *(const short8v*)(AsH + am[m]);
      al[m] = *(const short8v*)(AsL + am[m]);
    }
#pragma unroll
    for (int n = 0; n < 4; ++n) {
      bh[n] = *(const short8v*)(WsH + bo[n]);
      bl[n] = *(const short8v*)(WsL + bo[n]);
    }
#pragma unroll
    for (int m = 0; m < 4; ++m)
#pragma unroll
      for (int n = 0; n < 4; ++n) {
        acc[m][n] = __builtin_amdgcn_mfma_f32_16x16x32_bf16(ah[m], bh[n], acc[m][n], 0, 0, 0);
        acc[m][n] = __builtin_amdgcn_mfma_f32_16x16x32_bf16(ah[m], bl[n], acc[m][n], 0, 0, 0);
        acc[m][n] = __builtin_amdgcn_mfma_f32_16x16x32_bf16(al[m], bh[n], acc[m][n], 0, 0, 0);
      }
    __syncthreads();
  }

  float bvn[4];
#pragma unroll
  for (int n = 0; n < 4; ++n) bvn[n] = bias[bn + wc + n * 16 + laneM];
#pragma unroll
  for (int m = 0; m < 4; ++m)
#pragma unroll
    for (int n = 0; n < 4; ++n)
#pragma unroll
      for (int r = 0; r < 4; ++r) {
        float vv = acc[m][n][r] + bvn[n];
        if (act) vv = 0.5f * vv * (1.0f + erff(vv * 0.70710678118654752f));
        size_t row = (size_t)(bm + wr + m * 16 + laneK * 4 + r);
        int col = bn + wc + n * 16 + laneM;
        if (emit == 0) {
          Cf[row * N + col] = vv;
        } else if (emit == 1) {
          short hh, ll; split2(vv, hh, ll);
          Ch[row * N + col] = hh; Cl[row * N + col] = ll;
        } else if (emit == 2) {   // head-major [NH][Mrows][32]
          size_t idx = ((size_t)(col >> 5) * Mrows + row) * 32 + (col & 31);
          short hh, ll; split2(vv, hh, ll);
          Ch[idx] = hh; Cl[idx] = ll;
        } else {                  // V^T [NH][32][Mrows]
          size_t idx = ((size_t)(col >> 5) * 32 + (col & 31)) * Mrows + row;
          short hh, ll; split2(vv, hh, ll);
          Ch[idx] = hh; Cl[idx] = ll;
        }
      }
}

// ---------------- LayerNorm over last dim (256) -> split bf16 --------------
__global__ __launch_bounds__(256) void ln_kernel(const float* __restrict__ h,
    const float* __restrict__ w, const float* __restrict__ b,
    short* __restrict__ oH, short* __restrict__ oL, int M) {
  int row = blockIdx.x * 4 + (threadIdx.x >> 6);
  int lane = threadIdx.x & 63;
  if (row >= M) return;
  float4 v = *(const float4*)&h[(size_t)row * C_DIM + lane * 4];
  float s  = v.x + v.y + v.z + v.w;
  float s2 = v.x * v.x + v.y * v.y + v.z * v.z + v.w * v.w;
#pragma unroll
  for (int off = 1; off < 64; off <<= 1) { s += __shfl_xor(s, off); s2 += __shfl_xor(s2, off); }
  float mu  = s  * (1.0f / 256.0f);
  float var = s2 * (1.0f / 256.0f) - mu * mu;
  float inv = rsqrtf(var + 1e-5f);
  float4 wv = *(const float4*)&w[lane * 4];
  float4 bv = *(const float4*)&b[lane * 4];
  float o0 = (v.x - mu) * inv * wv.x + bv.x;
  float o1 = (v.y - mu) * inv * wv.y + bv.y;
  float o2 = (v.z - mu) * inv * wv.z + bv.z;
  float o3 = (v.w - mu) * inv * wv.w + bv.w;
  short h0,h1,h2,h3,l0,l1,l2,l3;
  split2(o0,h0,l0); split2(o1,h1,l1); split2(o2,h2,l2); split2(o3,h3,l3);
  size_t off = (size_t)row * C_DIM + lane * 4;
  *(short4*)&oH[off] = make_short4(h0,h1,h2,h3);
  *(short4*)&oL[off] = make_short4(l0,l1,l2,l3);
}

// ---------------- MFMA flash attention v3 ----------------------------------
// R10 post-mortem: register prefetch didn't survive compilation (VGPR stayed
// 56 -> loads re-sunk). v3 instead shares operands: all 4 waves of a block
// consume IDENTICAL K/V frags, so stage K/V tiles into LDS once per block via
// global_load_lds (GEMM-verified pattern), barrier, read frags from LDS.
// 4x VMEM cut; dependent chain becomes ds_read (~120cy) not L2 (200-900cy);
// TLP from 4 blocks/CU covers the staging wait (GEMM-proven structure).
// K staged linear [64][32] with XOR-swizzled SOURCE (rule 21: inverse-swz
// source + linear dest + swz read = the R8 GEMM's exact staging); V staged
// [32][64] with source swizzle g^=d&7. Frag reads spread uniformly over the
// 8 bank-groups. Swapped-QK^T softmax + rotated P layout kept from R10.
// Early return only when BLOCK-uniform (qt8*64>=lx); partial waves stay for
// barriers, outputs guarded.
__global__ __launch_bounds__(256, 4) void attn_mfma(
    const short* __restrict__ qh, const short* __restrict__ ql,   // [NH][Nx][32]
    const short* __restrict__ kh, const short* __restrict__ kl,   // [NH][Ne][32]
    const short* __restrict__ vh, const short* __restrict__ vl,   // [NH][32][Ne]
    const int* __restrict__ sx, const int* __restrict__ se,
    const int* __restrict__ emask,
    short* __restrict__ yH, short* __restrict__ yL,               // [Nx][256]
    int Nx, int Ne) {
  __shared__ short KsH[2048], KsL[2048];    // [64 tok][32 k], src-swizzled
  __shared__ short VsH[2048], VsL[2048];    // [32 d][64 tok], src-swizzled
  __shared__ short Ph[4][16][72];
  __shared__ short Pl[4][16][72];

  int bid = blockIdx.x;
  int work = ((bid & 7) << 9) + (bid >> 3);   // same (b,hd) group -> same XCD
  int qt8 = work & 7;
  int bh  = work >> 3;
  int b   = bh & 63;
  int hd  = bh >> 6;

  int xs = sx[b], lx = sx[b + 1] - xs;
  if (qt8 * 64 >= lx) return;             // BLOCK-uniform -> no barrier hazard
  int es = se[b], le = se[b + 1] - es;

  int tid = threadIdx.x;
  int wv = tid >> 6, lane = tid & 63;
  int qt = qt8 * 4 + wv;                  // this wave's 16-row q-tile
  int lm = lane & 15, lk = lane >> 4;

  // Q frag (B-operand of swapped QK^T): lane holds Q[q=lm][k=lk*8+j]
  int qa = xs + min(qt * 16 + lm, lx - 1);
  size_t qoff = ((size_t)hd * Nx + qa) * 32 + lk * 8;
  short8v qfh = *(const short8v*)(qh + qoff);
  short8v qfl = *(const short8v*)(ql + qoff);

  // staging source addresses (slot = tid; dest linear = base + tid*16B)
  int srow = tid >> 2;                         // K: token row 0..63
  int sc   = (tid & 3) ^ ((srow >> 1) & 3);    // K: swizzled k-granule
  int vd   = tid >> 3;                         // V: d row 0..31
  int vg   = (tid & 7) ^ (vd & 7);             // V: swizzled tok-granule
  const short* kbaseH = kh + (size_t)hd * Ne * 32 + srow * 32 + sc * 8;
  const short* kbaseL = kl + (size_t)hd * Ne * 32 + srow * 32 + sc * 8;
  const short* vbaseH = vh + ((size_t)hd * 32 + vd) * Ne + vg * 8;
  const short* vbaseL = vl + ((size_t)hd * 32 + vd) * Ne + vg * 8;
  short* dK = KsH + wv * 512;   // bytes: wv*1024
  short* dKl = KsL + wv * 512;
  short* dV = VsH + wv * 512;
  short* dVl = VsL + wv * 512;

  // frag read offsets (loop-invariant)
  int koff[4];
#pragma unroll
  for (int t = 0; t < 4; ++t)
    koff[t] = (t * 16 + lm) * 32 + ((lk ^ ((lm >> 1) & 3)) << 3);
  int voff0[2], voff1[2];
#pragma unroll
  for (int c = 0; c < 2; ++c) {
    voff0[c] = lm * 64        + (((c * 4 + lk) ^ (lm & 7)) << 3);
    voff1[c] = (16 + lm) * 64 + (((c * 4 + lk) ^ (lm & 7)) << 3);
  }

  float4v acc0 = {0.f,0.f,0.f,0.f}, acc1 = {0.f,0.f,0.f,0.f};
  float mrun = -INFINITY, lrun = 0.f;
  const float scale = 0.17677669529663689f;  // 1/sqrt(32)

  int kvend = es + le;
  for (int kb = (es >> 6) << 6; kb < kvend; kb += 64) {
    // ---- stage K/V tile into LDS (4 GLL, 16KB total per block)
    GLL(kbaseH + (size_t)kb * 32, dK);
    GLL(kbaseL + (size_t)kb * 32, dKl);
    GLL(vbaseH + kb, dV);
    GLL(vbaseL + kb, dVl);
    // mask loads (per-lane, tiny, L2-hot)
    int4 mk[4];
#pragma unroll
    for (int t = 0; t < 4; ++t)
      mk[t] = *(const int4*)(emask + min(kb + t * 16 + lk * 4, Ne - 4));
    __syncthreads();   // drains vmcnt -> staged tile visible

    // ---- swapped QK^T: S^T = K·Q^T; lane holds S[q=lm][kv=t*16+lk*4+r]
    float4v s[4];
#pragma unroll
    for (int t = 0; t < 4; ++t) {
      short8v kfh = *(const short8v*)(KsH + koff[t]);
      short8v kfl = *(const short8v*)(KsL + koff[t]);
      float4v z = {0.f,0.f,0.f,0.f};
      z = __builtin_amdgcn_mfma_f32_16x16x32_bf16(kfh, qfh, z, 0, 0, 0);
      z = __builtin_amdgcn_mfma_f32_16x16x32_bf16(kfh, qfl, z, 0, 0, 0);
      z = __builtin_amdgcn_mfma_f32_16x16x32_bf16(kfl, qfh, z, 0, 0, 0);
      s[t] = z;
    }

    // ---- per-lane online softmax for q = lm
    float pv[4][4];
    float mloc = -INFINITY;
#pragma unroll
    for (int t = 0; t < 4; ++t) {
      int tb = kb + t * 16 + lk * 4;
#pragma unroll
      for (int r = 0; r < 4; ++r) {
        int tok = tb + r;
        int mval = (r == 0) ? mk[t].x : (r == 1) ? mk[t].y : (r == 2) ? mk[t].z : mk[t].w;
        float bias = (tok >= es && tok < kvend && mval != 0) ? 0.f : -1e30f;
        float pp = s[t][r] * scale + bias;
        pv[t][r] = pp;
        mloc = fmaxf(mloc, pp);
      }
    }
    mloc = fmaxf(mloc, __shfl_xor(mloc, 16));
    mloc = fmaxf(mloc, __shfl_xor(mloc, 32));
    float mnew = fmaxf(mrun, mloc);
    float alpha = __expf(mrun - mnew);      // first tile: exp(-inf)=0
    float lloc = 0.f;
#pragma unroll
    for (int t = 0; t < 4; ++t) {
      short hs[4], ls[4];
#pragma unroll
      for (int r = 0; r < 4; ++r) {
        float e = __expf(pv[t][r] - mnew);
        lloc += e;
        split2(e, hs[r], ls[r]);
      }
      int kvg = 2 * t + (lk >> 1);          // granule of kv = t*16+lk*4
      int gs = (kvg - 2 * lm) & 7;          // rotate -> spread reads
      int off = gs * 8 + (lk & 1) * 4;
      *(short4*)&Ph[wv][lm][off] = make_short4(hs[0], hs[1], hs[2], hs[3]);
      *(short4*)&Pl[wv][lm][off] = make_short4(ls[0], ls[1], ls[2], ls[3]);
    }
    lloc += __shfl_xor(lloc, 16);
    lloc += __shfl_xor(lloc, 32);
    lrun = lrun * alpha + lloc;
    mrun = mnew;

    // ---- rescale acc (alpha lives at q=lm lanes; acc rows are q=lk*4+r)
#pragma unroll
    for (int r = 0; r < 4; ++r) {
      float aq = __shfl(alpha, lk * 4 + r);
      acc0[r] *= aq; acc1[r] *= aq;
    }

    // ---- PV: A=P (wave-private LDS, same-wave RAW), B=V^T rows from LDS
#pragma unroll
    for (int c = 0; c < 2; ++c) {
      int gs = ((4 * c + lk) - 2 * lm) & 7;
      short8v pfh = *(const short8v*)&Ph[wv][lm][gs * 8];
      short8v pfl = *(const short8v*)&Pl[wv][lm][gs * 8];
      short8v v0h = *(const short8v*)(VsH + voff0[c]);
      short8v v0l = *(const short8v*)(VsL + voff0[c]);
      short8v v1h = *(const short8v*)(VsH + voff1[c]);
      short8v v1l = *(const short8v*)(VsL + voff1[c]);
      acc0 = __builtin_amdgcn_mfma_f32_16x16x32_bf16(pfh, v0h, acc0, 0, 0, 0);
      acc0 = __builtin_amdgcn_mfma_f32_16x16x32_bf16(pfh, v0l, acc0, 0, 0, 0);
      acc0 = __builtin_amdgcn_mfma_f32_16x16x32_bf16(pfl, v0h, acc0, 0, 0, 0);
      acc1 = __builtin_amdgcn_mfma_f32_16x16x32_bf16(pfh, v1h, acc1, 0, 0, 0);
      acc1 = __builtin_amdgcn_mfma_f32_16x16x32_bf16(pfh, v1l, acc1, 0, 0, 0);
      acc1 = __builtin_amdgcn_mfma_f32_16x16x32_bf16(pfl, v1h, acc1, 0, 0, 0);
    }
    __syncthreads();   // protect Ks/Vs for next tile's staging
  }

  // ---- output: q = qt*16 + lk*4 + r, d = {lm, 16+lm}; invl via shfl
  float invl = (lrun > 0.f) ? 1.0f / lrun : 0.f;
  float iq[4];
#pragma unroll
  for (int r = 0; r < 4; ++r) iq[r] = __shfl(invl, lk * 4 + r);
#pragma unroll
  for (int r = 0; r < 4; ++r) {
    int q = qt * 16 + lk * 4 + r;
    if (q >= lx) continue;
    size_t base = (size_t)(xs + q) * C_DIM + hd * HDIM;
    short hh, ll;
    split2(acc0[r] * iq[r], hh, ll); yH[base + lm] = hh;      yL[base + lm] = ll;
    split2(acc1[r] * iq[r], hh, ll); yH[base + 16 + lm] = hh; yL[base + 16 + lm] = ll;
  }
}

// ---------------- launch ----------------
extern "C" void kernel_launch(void* const* d_in, const int* in_sizes, int n_in,
                              void* d_out, int out_size, void* d_ws, size_t ws_size,
                              hipStream_t stream) {
  const float* x    = (const float*)d_in[0];
  const int*   bx   = (const int*)d_in[1];
  const int*   be   = (const int*)d_in[2];
  const float* enc  = (const float*)d_in[3];
  const int*   msk  = (const int*)d_in[4];
  const float* Wq   = (const float*)d_in[5];
  const float* bq   = (const float*)d_in[6];
  const float* Wk   = (const float*)d_in[7];
  const float* bk   = (const float*)d_in[8];
  const float* Wv   = (const float*)d_in[9];
  const float* bv   = (const float*)d_in[10];
  const float* Wp   = (const float*)d_in[11];
  const float* bp   = (const float*)d_in[12];
  const float* W1   = (const float*)d_in[13];
  const float* b1   = (const float*)d_in[14];
  const float* W2   = (const float*)d_in[15];
  const float* b2   = (const float*)d_in[16];
  const float* lnw  = (const float*)d_in[17];
  const float* lnb  = (const float*)d_in[18];
  float* out = (float*)d_out;

  int Nx = in_sizes[0] / C_DIM;    // 24576 (multiple of 128, == Ne)
  int Ne = in_sizes[3] / IN_DIM;

  char* ws = (char*)d_ws;
  int* sx = (int*)ws;
  int* se = sx + 80;

  short* encH = (short*)(ws + 4096);                 // Ne*512
  short* encL = encH + (size_t)Ne * IN_DIM;          // Ne*512
  short* xH   = encL + (size_t)Ne * IN_DIM;          // Nx*256 (later yH)
  short* xL   = xH + (size_t)Nx * C_DIM;             // Nx*256 (later yL)
  short* gLo  = xL + (size_t)Nx * C_DIM;             // Ne*512 (later vH|vL)
  short* qHh  = gLo + (size_t)Ne * EMB_DIM;          // Nx*256
  short* qHl  = qHh + (size_t)Nx * C_DIM;            // Nx*256
  short* wbuf = qHl + (size_t)Nx * C_DIM;            // 1.31M shorts
  // reuses:
  short* gHi  = (short*)d_out;                       // G1 hi; dead after G2
  float* hbuf = (float*)encH;                        // enc splits dead post-G1
  short* hsH  = encL;
  short* hsL  = encL + (size_t)Ne * C_DIM;
  short* kH   = (short*)d_out;                       // after G2 (g dead)
  short* kL   = kH + (size_t)Ne * C_DIM;
  short* vH   = gLo;                                 // gLo dead after G2
  short* vL   = gLo + (size_t)Ne * C_DIM;

  short* w1tH = wbuf;               short* w1tL = w1tH + 512*512;
  short* w2tH = w1tL + 512*512;     short* w2tL = w2tH + 256*512;
  short* wqtH = w2tL + 256*512;     short* wqtL = wqtH + 256*256;
  short* wktH = wqtL + 256*256;     short* wktL = wktH + 256*256;
  short* wvtH = wktL + 256*256;     short* wvtL = wvtH + 256*256;
  short* wptH = wvtL + 256*256;     short* wptL = wptH + 256*256;

  prep_kernel<<<2048, 256, 0, stream>>>(enc, x, W1, W2, Wq, Wk, Wv, Wp,
      encH, encL, xH, xL, wbuf, Ne * IN_DIM, Nx * C_DIM);
  starts_kernel<<<1, 128, 0, stream>>>(bx, Nx, be, Ne, sx, se);

  int gy = Nx / 128;

  // G1: g = GELU(enc@W1+b1) -> split std ; Q: x@Wq+bq -> head-major split
  gemm_mfma<<<dim3(6, gy), 256, 0, stream>>>(
      encH, encL, w1tH, w1tL, b1, nullptr, gHi, gLo, IN_DIM, EMB_DIM, 1, 1,
      xH,   xL,   wqtH, wqtL, bq, nullptr, qHh, qHl,  C_DIM, C_DIM,  0, 2,
      4, Nx);

  // G2: h = g@W2+b2 (fp32)
  gemm_mfma<<<dim3(2, gy), 256, 0, stream>>>(
      gHi, gLo, w2tH, w2tL, b2, hbuf, nullptr, nullptr, EMB_DIM, C_DIM, 0, 0,
      gHi, gLo, w2tH, w2tL, b2, hbuf, nullptr, nullptr, EMB_DIM, C_DIM, 0, 0,
      2, Nx);

  ln_kernel<<<(Ne + 3) / 4, 256, 0, stream>>>(hbuf, lnw, lnb, hsH, hsL, Ne);

  // KV: K -> head-major split ; V -> V^T split (one A pass)
  gemm_mfma<<<dim3(4, gy), 256, 0, stream>>>(
      hsH, hsL, wktH, wktL, bk, nullptr, kH, kL, C_DIM, C_DIM, 0, 2,
      hsH, hsL, wvtH, wvtL, bv, nullptr, vH, vL, C_DIM, C_DIM, 0, 3,
      2, Nx);

  // MFMA attention -> y splits (over x region; x dead after G1)
  attn_mfma<<<dim3(4096), 256, 0, stream>>>(
      qHh, qHl, kH, kL, vH, vL, sx, se, msk, xH, xL, Nx, Ne);

  // P: out = y@Wp+bp (fp32)
  gemm_mfma<<<dim3(2, gy), 256, 0, stream>>>(
      xH, xL, wptH, wptL, bp, out, nullptr, nullptr, C_DIM, C_DIM, 0, 0,
      xH, xL, wptH, wptL, bp, out, nullptr, nullptr, C_DIM, C_DIM, 0, 0,
      2, Nx);
}

// Round 12
// 318.056 us; speedup vs baseline: 1.4257x; 1.1361x over previous
//
#include <hip/hip_runtime.h>
#include <math.h>

#define B_GROUPS 64
#define C_DIM 256
#define IN_DIM 512
#define EMB_DIM 512
#define NHEADS 8
#define HDIM 32

typedef __attribute__((ext_vector_type(8))) short short8v;   // 8 bf16 = 4 VGPR
typedef __attribute__((ext_vector_type(4))) float float4v;   // mfma acc

// split fp32 -> bf16 hi (truncate, residual exact) + bf16 lo (rounded)
__device__ __forceinline__ void split2(float x, short& hi, short& lo) {
  unsigned u = __float_as_uint(x);
  hi = (short)(u >> 16);
  float l = x - __uint_as_float(u & 0xffff0000u);   // exact
  unsigned ul = __float_as_uint(l);
  lo = (short)((ul + 0x8000u) >> 16);
}

// global -> LDS direct copy, 16B per lane (dest linear: base + lane*16)
#define GLL(src, dst) __builtin_amdgcn_global_load_lds( \
    (const __attribute__((address_space(1))) void*)(src), \
    (__attribute__((address_space(3))) void*)(dst), 16, 0, 0)

// ---------------- per-group starts via binary search ----------------
__global__ void starts_kernel(const int* __restrict__ bx, int nx,
                              const int* __restrict__ be, int ne,
                              int* __restrict__ sx, int* __restrict__ se) {
  int b = threadIdx.x;
  if (b > B_GROUPS) return;
  int lo = 0, hi = nx;
  while (lo < hi) { int mid = (lo + hi) >> 1; if (bx[mid] < b) lo = mid + 1; else hi = mid; }
  sx[b] = lo;
  lo = 0; hi = ne;
  while (lo < hi) { int mid = (lo + hi) >> 1; if (be[mid] < b) lo = mid + 1; else hi = mid; }
  se[b] = lo;
}

// ---------------- prep: split enc,x ; transpose+split weights ----------------
__global__ __launch_bounds__(256) void prep_kernel(
    const float* __restrict__ enc, const float* __restrict__ x,
    const float* __restrict__ W1, const float* __restrict__ W2,
    const float* __restrict__ Wq, const float* __restrict__ Wk,
    const float* __restrict__ Wv, const float* __restrict__ Wp,
    short* __restrict__ encH, short* __restrict__ encL,
    short* __restrict__ xH, short* __restrict__ xL,
    short* __restrict__ wbuf, int nEnc, int nX) {
  int gid = blockIdx.x * blockDim.x + threadIdx.x;
  int stride = gridDim.x * blockDim.x;
  for (int i = gid; i < nEnc; i += stride) { short h,l; split2(enc[i],h,l); encH[i]=h; encL[i]=l; }
  for (int i = gid; i < nX;   i += stride) { short h,l; split2(x[i],h,l);   xH[i]=h;   xL[i]=l; }
  short* w1tH = wbuf;               short* w1tL = w1tH + 512*512;
  short* w2tH = w1tL + 512*512;     short* w2tL = w2tH + 256*512;
  short* wqtH = w2tL + 256*512;     short* wqtL = wqtH + 256*256;
  short* wktH = wqtL + 256*256;     short* wktL = wktH + 256*256;
  short* wvtH = wktL + 256*256;     short* wvtL = wvtH + 256*256;
  short* wptH = wvtL + 256*256;     short* wptL = wptH + 256*256;
  for (int i = gid; i < 512*512; i += stride) {
    int n = i >> 9, k = i & 511; short h,l;
    split2(W1[k*512 + n], h, l); w1tH[i] = h; w1tL[i] = l;
  }
  for (int i = gid; i < 256*512; i += stride) {
    int n = i >> 9, k = i & 511; short h,l;
    split2(W2[k*256 + n], h, l); w2tH[i] = h; w2tL[i] = l;
  }
  for (int i = gid; i < 256*256; i += stride) {
    int n = i >> 8, k = i & 255; int s = k*256 + n; short h,l;
    split2(Wq[s],h,l); wqtH[i]=h; wqtL[i]=l;
    split2(Wk[s],h,l); wktH[i]=h; wktL[i]=l;
    split2(Wv[s],h,l); wvtH[i]=h; wvtL[i]=l;
    split2(Wp[s],h,l); wptH[i]=h; wptL[i]=l;
  }
}

// ---------------- bf16x2-split MFMA GEMM: 128x128 tile, 4 waves ------------
// v13: (a) 1D grid, XCD-chunked bijective swizzle (same-A-row blocks land on
// one XCD -> panel L2 reuse; all grids %8==0). (b) For emit 0/1/2 the MFMA
// operands are SWAPPED (mfma(W,A) = transpose) so each lane owns 4 CONSECUTIVE
// output columns -> float4/short4 packed coalesced stores (was 4-8x scalar
// 2B stores). emit 3 (V^T) keeps original order: there 4 consecutive ROWS are
// contiguous in the output index -> packed over r.
__global__ __launch_bounds__(256) void gemm_mfma(
    const short* __restrict__ Ah0, const short* __restrict__ Al0,
    const short* __restrict__ Wh0, const short* __restrict__ Wl0,
    const float* __restrict__ bias0, float* __restrict__ Cf0,
    short* __restrict__ Ch0, short* __restrict__ Cl0,
    int K0, int N0, int act0, int emit0,
    const short* __restrict__ Ah1, const short* __restrict__ Al1,
    const short* __restrict__ Wh1, const short* __restrict__ Wl1,
    const float* __restrict__ bias1, float* __restrict__ Cf1,
    short* __restrict__ Ch1, short* __restrict__ Cl1,
    int K1, int N1, int act1, int emit1,
    int xsplit, int Mrows, int gx) {
  __shared__ short AsH[4096], AsL[4096], WsH[4096], WsL[4096];   // 4x8KB

  // XCD-chunked bijective swizzle (nwg % 8 == 0 for all our launches)
  int nwg = gridDim.x;
  int cpx = nwg >> 3;
  int bid = blockIdx.x;
  int w = ((bid & 7) * cpx) + (bid >> 3);
  int bxi = w % gx;
  int byi = w / gx;

  const short *Ah, *Al, *Wh, *Wl; const float* bias; float* Cf; short *Ch, *Cl;
  int K, N, act, emit;
  if (bxi < xsplit) {
    Ah=Ah0; Al=Al0; Wh=Wh0; Wl=Wl0; bias=bias0; Cf=Cf0; Ch=Ch0; Cl=Cl0;
    K=K0; N=N0; act=act0; emit=emit0;
  } else {
    bxi -= xsplit;
    Ah=Ah1; Al=Al1; Wh=Wh1; Wl=Wl1; bias=bias1; Cf=Cf1; Ch=Ch1; Cl=Cl1;
    K=K1; N=N1; act=act1; emit=emit1;
  }
  int bm = byi * 128;
  int bn = bxi * 128;

  int tid = threadIdx.x;
  int wv = tid >> 6, lane = tid & 63;
  int wr = (wv >> 1) * 64, wc = (wv & 1) * 64;
  int laneM = lane & 15, laneK = lane >> 4;

  int Ga = wv * 128 + lane;
  int Gb = Ga + 64;
  int rA = Ga >> 2, gA = (Ga & 3) ^ ((rA >> 1) & 3);
  int rB = Gb >> 2, gB = (Gb & 3) ^ ((rB >> 1) & 3);
  const short* pAh0 = Ah + (size_t)(bm + rA) * K + gA * 8;
  const short* pAh1 = Ah + (size_t)(bm + rB) * K + gB * 8;
  const short* pAl0 = Al + (size_t)(bm + rA) * K + gA * 8;
  const short* pAl1 = Al + (size_t)(bm + rB) * K + gB * 8;
  const short* pWh0 = Wh + (size_t)(bn + rA) * K + gA * 8;
  const short* pWh1 = Wh + (size_t)(bn + rB) * K + gB * 8;
  const short* pWl0 = Wl + (size_t)(bn + rA) * K + gA * 8;
  const short* pWl1 = Wl + (size_t)(bn + rB) * K + gB * 8;
  short* dAH0 = AsH + wv * 1024;  short* dAH1 = dAH0 + 512;
  short* dAL0 = AsL + wv * 1024;  short* dAL1 = dAL0 + 512;
  short* dWH0 = WsH + wv * 1024;  short* dWH1 = dWH0 + 512;
  short* dWL0 = WsL + wv * 1024;  short* dWL1 = dWL0 + 512;

  int am[4], bo[4];
#pragma unroll
  for (int m = 0; m < 4; ++m) {
    int row = wr + m * 16 + laneM;
    am[m] = row * 32 + ((laneK ^ ((row >> 1) & 3)) << 3);
  }
#pragma unroll
  for (int n = 0; n < 4; ++n) {
    int row = wc + n * 16 + laneM;
    bo[n] = row * 32 + ((laneK ^ ((row >> 1) & 3)) << 3);
  }

  float4v acc[4][4];
  float4v z4 = {0.f, 0.f, 0.f, 0.f};
#pragma unroll
  for (int m = 0; m < 4; ++m)
#pragma unroll
    for (int n = 0; n < 4; ++n) acc[m][n] = z4;

  int nsteps = K >> 5;
  for (int t = 0; t < nsteps; ++t) {
    GLL(pAh0, dAH0); GLL(pAh1, dAH1);
    GLL(pAl0, dAL0); GLL(pAl1, dAL1);
    GLL(pWh0, dWH0); GLL(pWh1, dWH1);
    GLL(pWl0, dWL0); GLL(pWl1, dWL1);
    pAh0 += 32; pAh1 += 32; pAl0 += 32; pAl1 += 32;
    pWh0 += 32; pWh1 += 32; pWl0 += 32; pWl1 += 32;
    __syncthreads();

    short8v ah[4], al[4], bh[4], bl[4];
#pragma unroll
    for (int m = 0; m < 4; ++m) {
      ah[m] = *(const short8v*)(AsH + am[m]);
      al[m] = *(const short8v*)(AsL + am[m]);
    }
#pragma unroll
    for (int n = 0; n < 4; ++n) {
      bh[n] = *(const short8v*)(WsH + bo[n]);
      bl[n] = *(const short8v*)(WsL + bo[n]);
    }
    if (emit != 3) {
      // swapped: D[row=n-frag rows][col=m-frag rows] -> lane owns 4 consec cols
#pragma unroll
      for (int m = 0; m < 4; ++m)
#pragma unroll
        for (int n = 0; n < 4; ++n) {
          acc[m][n] = __builtin_amdgcn_mfma_f32_16x16x32_bf16(bh[n], ah[m], acc[m][n], 0, 0, 0);
          acc[m][n] = __builtin_amdgcn_mfma_f32_16x16x32_bf16(bh[n], al[m], acc[m][n], 0, 0, 0);
          acc[m][n] = __builtin_amdgcn_mfma_f32_16x16x32_bf16(bl[n], ah[m], acc[m][n], 0, 0, 0);
        }
    } else {
#pragma unroll
      for (int m = 0; m < 4; ++m)
#pragma unroll
        for (int n = 0; n < 4; ++n) {
          acc[m][n] = __builtin_amdgcn_mfma_f32_16x16x32_bf16(ah[m], bh[n], acc[m][n], 0, 0, 0);
          acc[m][n] = __builtin_amdgcn_mfma_f32_16x16x32_bf16(ah[m], bl[n], acc[m][n], 0, 0, 0);
          acc[m][n] = __builtin_amdgcn_mfma_f32_16x16x32_bf16(al[m], bh[n], acc[m][n], 0, 0, 0);
        }
    }
    __syncthreads();
  }

  if (emit != 3) {
    // lane owns row = bm+wr+m*16+laneM, cols bn+wc+n*16+laneK*4 .. +3
#pragma unroll
    for (int m = 0; m < 4; ++m) {
      size_t row = (size_t)(bm + wr + m * 16 + laneM);
#pragma unroll
      for (int n = 0; n < 4; ++n) {
        int colb = bn + wc + n * 16 + laneK * 4;
        float4 bv4 = *(const float4*)&bias[colb];
        float o[4];
        o[0] = acc[m][n][0] + bv4.x; o[1] = acc[m][n][1] + bv4.y;
        o[2] = acc[m][n][2] + bv4.z; o[3] = acc[m][n][3] + bv4.w;
        if (act) {
#pragma unroll
          for (int r = 0; r < 4; ++r)
            o[r] = 0.5f * o[r] * (1.0f + erff(o[r] * 0.70710678118654752f));
        }
        if (emit == 0) {
          *(float4*)&Cf[row * N + colb] = make_float4(o[0], o[1], o[2], o[3]);
        } else if (emit == 1) {
          short hs[4], ls[4];
#pragma unroll
          for (int r = 0; r < 4; ++r) split2(o[r], hs[r], ls[r]);
          *(short4*)&Ch[row * N + colb] = make_short4(hs[0], hs[1], hs[2], hs[3]);
          *(short4*)&Cl[row * N + colb] = make_short4(ls[0], ls[1], ls[2], ls[3]);
        } else {   // emit 2: head-major [NH][Mrows][32]; 4 cols stay in-head
          size_t idx = ((size_t)(colb >> 5) * Mrows + row) * 32 + (colb & 31);
          short hs[4], ls[4];
#pragma unroll
          for (int r = 0; r < 4; ++r) split2(o[r], hs[r], ls[r]);
          *(short4*)&Ch[idx] = make_short4(hs[0], hs[1], hs[2], hs[3]);
          *(short4*)&Cl[idx] = make_short4(ls[0], ls[1], ls[2], ls[3]);
        }
      }
    }
  } else {
    // emit 3 (V^T [NH][32][Mrows]): original order; 4 consec rows -> packed
    float bvn[4];
#pragma unroll
    for (int n = 0; n < 4; ++n) bvn[n] = bias[bn + wc + n * 16 + laneM];
#pragma unroll
    for (int m = 0; m < 4; ++m)
#pragma unroll
      for (int n = 0; n < 4; ++n) {
        int col = bn + wc + n * 16 + laneM;
        size_t row0 = (size_t)(bm + wr + m * 16 + laneK * 4);
        size_t idx = ((size_t)(col >> 5) * 32 + (col & 31)) * Mrows + row0;
        short hs[4], ls[4];
#pragma unroll
        for (int r = 0; r < 4; ++r) split2(acc[m][n][r] + bvn[n], hs[r], ls[r]);
        *(short4*)&Ch[idx] = make_short4(hs[0], hs[1], hs[2], hs[3]);
        *(short4*)&Cl[idx] = make_short4(ls[0], ls[1], ls[2], ls[3]);
      }
  }
}

// ---------------- LayerNorm over last dim (256) -> split bf16 --------------
__global__ __launch_bounds__(256) void ln_kernel(const float* __restrict__ h,
    const float* __restrict__ w, const float* __restrict__ b,
    short* __restrict__ oH, short* __restrict__ oL, int M) {
  int row = blockIdx.x * 4 + (threadIdx.x >> 6);
  int lane = threadIdx.x & 63;
  if (row >= M) return;
  float4 v = *(const float4*)&h[(size_t)row * C_DIM + lane * 4];
  float s  = v.x + v.y + v.z + v.w;
  float s2 = v.x * v.x + v.y * v.y + v.z * v.z + v.w * v.w;
#pragma unroll
  for (int off = 1; off < 64; off <<= 1) { s += __shfl_xor(s, off); s2 += __shfl_xor(s2, off); }
  float mu  = s  * (1.0f / 256.0f);
  float var = s2 * (1.0f / 256.0f) - mu * mu;
  float inv = rsqrtf(var + 1e-5f);
  float4 wv = *(const float4*)&w[lane * 4];
  float4 bv = *(const float4*)&b[lane * 4];
  float o0 = (v.x - mu) * inv * wv.x + bv.x;
  float o1 = (v.y - mu) * inv * wv.y + bv.y;
  float o2 = (v.z - mu) * inv * wv.z + bv.z;
  float o3 = (v.w - mu) * inv * wv.w + bv.w;
  short h0,h1,h2,h3,l0,l1,l2,l3;
  split2(o0,h0,l0); split2(o1,h1,l1); split2(o2,h2,l2); split2(o3,h3,l3);
  size_t off = (size_t)row * C_DIM + lane * 4;
  *(short4*)&oH[off] = make_short4(h0,h1,h2,h3);
  *(short4*)&oL[off] = make_short4(l0,l1,l2,l3);
}

// ---------------- MFMA flash attention v4 ----------------------------------
// v13 changes vs R11 (block-shared LDS staging kept verbatim): PV operands
// SWAPPED (mfma(V,P) -> lane owns O[q=lm][4 consecutive d]), so alpha/invl
// apply directly (no shfl re-broadcast) and y-stores pack as short4.
__global__ __launch_bounds__(256, 4) void attn_mfma(
    const short* __restrict__ qh, const short* __restrict__ ql,   // [NH][Nx][32]
    const short* __restrict__ kh, const short* __restrict__ kl,   // [NH][Ne][32]
    const short* __restrict__ vh, const short* __restrict__ vl,   // [NH][32][Ne]
    const int* __restrict__ sx, const int* __restrict__ se,
    const int* __restrict__ emask,
    short* __restrict__ yH, short* __restrict__ yL,               // [Nx][256]
    int Nx, int Ne) {
  __shared__ short KsH[2048], KsL[2048];    // [64 tok][32 k], src-swizzled
  __shared__ short VsH[2048], VsL[2048];    // [32 d][64 tok], src-swizzled
  __shared__ short Ph[4][16][72];
  __shared__ short Pl[4][16][72];

  int bid = blockIdx.x;
  int work = ((bid & 7) << 9) + (bid >> 3);   // same (b,hd) group -> same XCD
  int qt8 = work & 7;
  int bh  = work >> 3;
  int b   = bh & 63;
  int hd  = bh >> 6;

  int xs = sx[b], lx = sx[b + 1] - xs;
  if (qt8 * 64 >= lx) return;             // BLOCK-uniform -> no barrier hazard
  int es = se[b], le = se[b + 1] - es;

  int tid = threadIdx.x;
  int wv = tid >> 6, lane = tid & 63;
  int qt = qt8 * 4 + wv;                  // this wave's 16-row q-tile
  int lm = lane & 15, lk = lane >> 4;

  // Q frag (B-operand of swapped QK^T): lane holds Q[q=lm][k=lk*8+j]
  int qa = xs + min(qt * 16 + lm, lx - 1);
  size_t qoff = ((size_t)hd * Nx + qa) * 32 + lk * 8;
  short8v qfh = *(const short8v*)(qh + qoff);
  short8v qfl = *(const short8v*)(ql + qoff);

  // staging source addresses (slot = tid; dest linear = base + tid*16B)
  int srow = tid >> 2;                         // K: token row 0..63
  int sc   = (tid & 3) ^ ((srow >> 1) & 3);    // K: swizzled k-granule
  int vd   = tid >> 3;                         // V: d row 0..31
  int vg   = (tid & 7) ^ (vd & 7);             // V: swizzled tok-granule
  const short* kbaseH = kh + (size_t)hd * Ne * 32 + srow * 32 + sc * 8;
  const short* kbaseL = kl + (size_t)hd * Ne * 32 + srow * 32 + sc * 8;
  const short* vbaseH = vh + ((size_t)hd * 32 + vd) * Ne + vg * 8;
  const short* vbaseL = vl + ((size_t)hd * 32 + vd) * Ne + vg * 8;
  short* dK = KsH + wv * 512;
  short* dKl = KsL + wv * 512;
  short* dV = VsH + wv * 512;
  short* dVl = VsL + wv * 512;

  // frag read offsets (loop-invariant)
  int koff[4];
#pragma unroll
  for (int t = 0; t < 4; ++t)
    koff[t] = (t * 16 + lm) * 32 + ((lk ^ ((lm >> 1) & 3)) << 3);
  int voff0[2], voff1[2];
#pragma unroll
  for (int c = 0; c < 2; ++c) {
    voff0[c] = lm * 64        + (((c * 4 + lk) ^ (lm & 7)) << 3);
    voff1[c] = (16 + lm) * 64 + (((c * 4 + lk) ^ (lm & 7)) << 3);
  }

  float4v acc0 = {0.f,0.f,0.f,0.f}, acc1 = {0.f,0.f,0.f,0.f};
  float mrun = -INFINITY, lrun = 0.f;
  const float scale = 0.17677669529663689f;  // 1/sqrt(32)

  int kvend = es + le;
  for (int kb = (es >> 6) << 6; kb < kvend; kb += 64) {
    // ---- stage K/V tile into LDS (4 GLL, 16KB total per block)
    GLL(kbaseH + (size_t)kb * 32, dK);
    GLL(kbaseL + (size_t)kb * 32, dKl);
    GLL(vbaseH + kb, dV);
    GLL(vbaseL + kb, dVl);
    int4 mk[4];
#pragma unroll
    for (int t = 0; t < 4; ++t)
      mk[t] = *(const int4*)(emask + min(kb + t * 16 + lk * 4, Ne - 4));
    __syncthreads();   // drains vmcnt -> staged tile visible

    // ---- swapped QK^T: S^T = K·Q^T; lane holds S[q=lm][kv=t*16+lk*4+r]
    float4v s[4];
#pragma unroll
    for (int t = 0; t < 4; ++t) {
      short8v kfh = *(const short8v*)(KsH + koff[t]);
      short8v kfl = *(const short8v*)(KsL + koff[t]);
      float4v z = {0.f,0.f,0.f,0.f};
      z = __builtin_amdgcn_mfma_f32_16x16x32_bf16(kfh, qfh, z, 0, 0, 0);
      z = __builtin_amdgcn_mfma_f32_16x16x32_bf16(kfh, qfl, z, 0, 0, 0);
      z = __builtin_amdgcn_mfma_f32_16x16x32_bf16(kfl, qfh, z, 0, 0, 0);
      s[t] = z;
    }

    // ---- per-lane online softmax for q = lm
    float pv[4][4];
    float mloc = -INFINITY;
#pragma unroll
    for (int t = 0; t < 4; ++t) {
      int tb = kb + t * 16 + lk * 4;
#pragma unroll
      for (int r = 0; r < 4; ++r) {
        int tok = tb + r;
        int mval = (r == 0) ? mk[t].x : (r == 1) ? mk[t].y : (r == 2) ? mk[t].z : mk[t].w;
        float bias = (tok >= es && tok < kvend && mval != 0) ? 0.f : -1e30f;
        float pp = s[t][r] * scale + bias;
        pv[t][r] = pp;
        mloc = fmaxf(mloc, pp);
      }
    }
    mloc = fmaxf(mloc, __shfl_xor(mloc, 16));
    mloc = fmaxf(mloc, __shfl_xor(mloc, 32));
    float mnew = fmaxf(mrun, mloc);
    float alpha = __expf(mrun - mnew);      // first tile: exp(-inf)=0
    float lloc = 0.f;
#pragma unroll
    for (int t = 0; t < 4; ++t) {
      short hs[4], ls[4];
#pragma unroll
      for (int r = 0; r < 4; ++r) {
        float e = __expf(pv[t][r] - mnew);
        lloc += e;
        split2(e, hs[r], ls[r]);
      }
      int kvg = 2 * t + (lk >> 1);          // granule of kv = t*16+lk*4
      int gs = (kvg - 2 * lm) & 7;          // rotate -> spread reads
      int off = gs * 8 + (lk & 1) * 4;
      *(short4*)&Ph[wv][lm][off] = make_short4(hs[0], hs[1], hs[2], hs[3]);
      *(short4*)&Pl[wv][lm][off] = make_short4(ls[0], ls[1], ls[2], ls[3]);
    }
    lloc += __shfl_xor(lloc, 16);
    lloc += __shfl_xor(lloc, 32);
    lrun = lrun * alpha + lloc;
    mrun = mnew;

    // ---- rescale acc: acc cols are q=lm — alpha applies DIRECTLY
    acc0[0] *= alpha; acc0[1] *= alpha; acc0[2] *= alpha; acc0[3] *= alpha;
    acc1[0] *= alpha; acc1[1] *= alpha; acc1[2] *= alpha; acc1[3] *= alpha;

    // ---- PV swapped: mfma(V,P) -> O[q=lm][d=lk*4+r]; same LDS frags
#pragma unroll
    for (int c = 0; c < 2; ++c) {
      int gs = ((4 * c + lk) - 2 * lm) & 7;
      short8v pfh = *(const short8v*)&Ph[wv][lm][gs * 8];
      short8v pfl = *(const short8v*)&Pl[wv][lm][gs * 8];
      short8v v0h = *(const short8v*)(VsH + voff0[c]);
      short8v v0l = *(const short8v*)(VsL + voff0[c]);
      short8v v1h = *(const short8v*)(VsH + voff1[c]);
      short8v v1l = *(const short8v*)(VsL + voff1[c]);
      acc0 = __builtin_amdgcn_mfma_f32_16x16x32_bf16(v0h, pfh, acc0, 0, 0, 0);
      acc0 = __builtin_amdgcn_mfma_f32_16x16x32_bf16(v0h, pfl, acc0, 0, 0, 0);
      acc0 = __builtin_amdgcn_mfma_f32_16x16x32_bf16(v0l, pfh, acc0, 0, 0, 0);
      acc1 = __builtin_amdgcn_mfma_f32_16x16x32_bf16(v1h, pfh, acc1, 0, 0, 0);
      acc1 = __builtin_amdgcn_mfma_f32_16x16x32_bf16(v1h, pfl, acc1, 0, 0, 0);
      acc1 = __builtin_amdgcn_mfma_f32_16x16x32_bf16(v1l, pfh, acc1, 0, 0, 0);
    }
    __syncthreads();   // protect Ks/Vs for next tile's staging
  }

  // ---- output: lane owns q=qt*16+lm, d = lk*4+r and 16+lk*4+r -> short4
  int q = qt * 16 + lm;
  if (q < lx) {
    float invl = (lrun > 0.f) ? 1.0f / lrun : 0.f;
    size_t base = (size_t)(xs + q) * C_DIM + hd * HDIM;
    short hs[4], ls[4];
#pragma unroll
    for (int r = 0; r < 4; ++r) split2(acc0[r] * invl, hs[r], ls[r]);
    *(short4*)&yH[base + lk * 4] = make_short4(hs[0], hs[1], hs[2], hs[3]);
    *(short4*)&yL[base + lk * 4] = make_short4(ls[0], ls[1], ls[2], ls[3]);
#pragma unroll
    for (int r = 0; r < 4; ++r) split2(acc1[r] * invl, hs[r], ls[r]);
    *(short4*)&yH[base + 16 + lk * 4] = make_short4(hs[0], hs[1], hs[2], hs[3]);
    *(short4*)&yL[base + 16 + lk * 4] = make_short4(ls[0], ls[1], ls[2], ls[3]);
  }
}

// ---------------- launch ----------------
extern "C" void kernel_launch(void* const* d_in, const int* in_sizes, int n_in,
                              void* d_out, int out_size, void* d_ws, size_t ws_size,
                              hipStream_t stream) {
  const float* x    = (const float*)d_in[0];
  const int*   bx   = (const int*)d_in[1];
  const int*   be   = (const int*)d_in[2];
  const float* enc  = (const float*)d_in[3];
  const int*   msk  = (const int*)d_in[4];
  const float* Wq   = (const float*)d_in[5];
  const float* bq   = (const float*)d_in[6];
  const float* Wk   = (const float*)d_in[7];
  const float* bk   = (const float*)d_in[8];
  const float* Wv   = (const float*)d_in[9];
  const float* bv   = (const float*)d_in[10];
  const float* Wp   = (const float*)d_in[11];
  const float* bp   = (const float*)d_in[12];
  const float* W1   = (const float*)d_in[13];
  const float* b1   = (const float*)d_in[14];
  const float* W2   = (const float*)d_in[15];
  const float* b2   = (const float*)d_in[16];
  const float* lnw  = (const float*)d_in[17];
  const float* lnb  = (const float*)d_in[18];
  float* out = (float*)d_out;

  int Nx = in_sizes[0] / C_DIM;    // 24576 (multiple of 128, == Ne)
  int Ne = in_sizes[3] / IN_DIM;

  char* ws = (char*)d_ws;
  int* sx = (int*)ws;
  int* se = sx + 80;

  short* encH = (short*)(ws + 4096);                 // Ne*512
  short* encL = encH + (size_t)Ne * IN_DIM;          // Ne*512
  short* xH   = encL + (size_t)Ne * IN_DIM;          // Nx*256 (later yH)
  short* xL   = xH + (size_t)Nx * C_DIM;             // Nx*256 (later yL)
  short* gLo  = xL + (size_t)Nx * C_DIM;             // Ne*512 (later vH|vL)
  short* qHh  = gLo + (size_t)Ne * EMB_DIM;          // Nx*256
  short* qHl  = qHh + (size_t)Nx * C_DIM;            // Nx*256
  short* wbuf = qHl + (size_t)Nx * C_DIM;            // 1.31M shorts
  // reuses:
  short* gHi  = (short*)d_out;                       // G1 hi; dead after G2
  float* hbuf = (float*)encH;                        // enc splits dead post-G1
  short* hsH  = encL;
  short* hsL  = encL + (size_t)Ne * C_DIM;
  short* kH   = (short*)d_out;                       // after G2 (g dead)
  short* kL   = kH + (size_t)Ne * C_DIM;
  short* vH   = gLo;                                 // gLo dead after G2
  short* vL   = gLo + (size_t)Ne * C_DIM;

  short* w1tH = wbuf;               short* w1tL = w1tH + 512*512;
  short* w2tH = w1tL + 512*512;     short* w2tL = w2tH + 256*512;
  short* wqtH = w2tL + 256*512;     short* wqtL = wqtH + 256*256;
  short* wktH = wqtL + 256*256;     short* wktL = wktH + 256*256;
  short* wvtH = wktL + 256*256;     short* wvtL = wvtH + 256*256;
  short* wptH = wvtL + 256*256;     short* wptL = wptH + 256*256;

  prep_kernel<<<2048, 256, 0, stream>>>(enc, x, W1, W2, Wq, Wk, Wv, Wp,
      encH, encL, xH, xL, wbuf, Ne * IN_DIM, Nx * C_DIM);
  starts_kernel<<<1, 128, 0, stream>>>(bx, Nx, be, Ne, sx, se);

  int gy = Nx / 128;   // 192

  // G1: g = GELU(enc@W1+b1) -> split std ; Q: x@Wq+bq -> head-major split
  gemm_mfma<<<dim3(6 * gy), 256, 0, stream>>>(
      encH, encL, w1tH, w1tL, b1, nullptr, gHi, gLo, IN_DIM, EMB_DIM, 1, 1,
      xH,   xL,   wqtH, wqtL, bq, nullptr, qHh, qHl,  C_DIM, C_DIM,  0, 2,
      4, Nx, 6);

  // G2: h = g@W2+b2 (fp32)
  gemm_mfma<<<dim3(2 * gy), 256, 0, stream>>>(
      gHi, gLo, w2tH, w2tL, b2, hbuf, nullptr, nullptr, EMB_DIM, C_DIM, 0, 0,
      gHi, gLo, w2tH, w2tL, b2, hbuf, nullptr, nullptr, EMB_DIM, C_DIM, 0, 0,
      2, Nx, 2);

  ln_kernel<<<(Ne + 3) / 4, 256, 0, stream>>>(hbuf, lnw, lnb, hsH, hsL, Ne);

  // KV: K -> head-major split (swapped) ; V -> V^T split (original order)
  gemm_mfma<<<dim3(4 * gy), 256, 0, stream>>>(
      hsH, hsL, wktH, wktL, bk, nullptr, kH, kL, C_DIM, C_DIM, 0, 2,
      hsH, hsL, wvtH, wvtL, bv, nullptr, vH, vL, C_DIM, C_DIM, 0, 3,
      2, Nx, 4);

  // MFMA attention -> y splits (over x region; x dead after G1)
  attn_mfma<<<dim3(4096), 256, 0, stream>>>(
      qHh, qHl, kH, kL, vH, vL, sx, se, msk, xH, xL, Nx, Ne);

  // P: out = y@Wp+bp (fp32)
  gemm_mfma<<<dim3(2 * gy), 256, 0, stream>>>(
      xH, xL, wptH, wptL, bp, out, nullptr, nullptr, C_DIM, C_DIM, 0, 0,
      xH, xL, wptH, wptL, bp, out, nullptr, nullptr, C_DIM, C_DIM, 0, 0,
      2, Nx, 2);
}